// Round 4
// baseline (101.958 us; speedup 1.0000x reference)
//
#include <hip/hip_runtime.h>

#define B_ 512
#define S_ 4
#define K_ 912
#define R_ 8
#define D_ 912
#define NCODE 1824
#define BSK (B_*S_*K_)   /* 1867776 */
#define BP_ITERS 10
#define NTH 228          /* 4*228 = 912 */

// one-thread kernel: compute no / noise-scale once (fp64 pow off the hot path)
__global__ void setup_kernel(const int* __restrict__ ebno, float* __restrict__ cst) {
  int ei = ebno[0];
  float ef = (ei >= -100 && ei <= 100) ? (float)ei : __int_as_float(ei);
  double no_d = pow(10.0, -(double)ef / 10.0);
  cst[0] = (float)no_d;
  cst[1] = (float)sqrt(no_d * 0.5);
}

#define BFLY(v) { v += __shfl_xor(v, 1); v += __shfl_xor(v, 2); v += __shfl_xor(v, 4); }

// 8 lanes per (b,d): lane r owns receive antenna r. Coalesced float4 loads,
// rank-1 A/w contributions, butterfly-reduced in-wave, solve duplicated.
__global__ __launch_bounds__(256) void mmse_llr_kernel(
    const int* __restrict__ bbits, const float* __restrict__ hre,
    const float* __restrict__ him, const float* __restrict__ nre,
    const float* __restrict__ nim, const float* __restrict__ cst,
    float* __restrict__ outf) {
#pragma clang fp contract(off)
  int t = blockIdx.x * 256 + threadIdx.x;
  int g = t >> 3;          // (b,d) group index
  int r = t & 7;           // receive antenna owned by this lane
  int b = g / D_;
  int d = g - b * D_;

  const float no_f = cst[0];
  const float nscale = cst[1];
  const float INV2 = 0.70710678118654752440f;

  // --- QPSK symbols for the 4 streams at subcarrier d (dup across 8 lanes) ---
  float xr[S_], xq[S_];
  int k2 = 2 * d;
#pragma unroll
  for (int s = 0; s < S_; ++s) {
    const int* bb = bbits + (b * S_ + s) * K_;
    int c0, c1;
    if (k2 < K_) {
      c0 = bb[k2];
      c1 = bb[k2 + 1];
    } else {
      int j0 = k2 - K_, j1 = k2 + 1 - K_;
      int j0a = j0 - 7;   if (j0a < 0) j0a += K_;
      int j0b = j0 - 150; if (j0b < 0) j0b += K_;
      c0 = (bb[j0] + bb[j0a] + bb[j0b]) & 1;
      int j1a = j1 - 7;   if (j1a < 0) j1a += K_;
      int j1b = j1 - 150; if (j1b < 0) j1b += K_;
      c1 = (bb[j1] + bb[j1a] + bb[j1b]) & 1;
    }
    xr[s] = (1.0f - 2.0f * (float)c0) * INV2;
    xq[s] = (1.0f - 2.0f * (float)c1) * INV2;
  }

  // --- this lane's h row (perfectly coalesced: float4 at global tid) ---
  float4 h4r = reinterpret_cast<const float4*>(hre)[t];
  float4 h4i = reinterpret_cast<const float4*>(him)[t];
  float hr0=h4r.x*INV2, hr1=h4r.y*INV2, hr2=h4r.z*INV2, hr3=h4r.w*INV2;
  float hi0=h4i.x*INV2, hi1=h4i.y*INV2, hi2=h4i.z*INV2, hi3=h4i.w*INV2;

  // --- y_r = sum_s h[r][s]*x[s] + noise (same op order as before) ---
  float yr = 0.f, yi = 0.f;
  yr += hr0*xr[0] - hi0*xq[0]; yi += hr0*xq[0] + hi0*xr[0];
  yr += hr1*xr[1] - hi1*xq[1]; yi += hr1*xq[1] + hi1*xr[1];
  yr += hr2*xr[2] - hi2*xq[2]; yi += hr2*xq[2] + hi2*xr[2];
  yr += hr3*xr[3] - hi3*xq[3]; yi += hr3*xq[3] + hi3*xr[3];
  yr += nre[t] * nscale;
  yi += nim[t] * nscale;

  // --- rank-1 contributions to A (lower tri) and w = H^H y ---
  float Ad0 = hr0*hr0 + hi0*hi0;
  float Ad1 = hr1*hr1 + hi1*hi1;
  float Ad2 = hr2*hr2 + hi2*hi2;
  float Ad3 = hr3*hr3 + hi3*hi3;
  float A10r = hr1*hr0 + hi1*hi0, A10i = hr1*hi0 - hi1*hr0;
  float A20r = hr2*hr0 + hi2*hi0, A20i = hr2*hi0 - hi2*hr0;
  float A21r = hr2*hr1 + hi2*hi1, A21i = hr2*hi1 - hi2*hr1;
  float A30r = hr3*hr0 + hi3*hi0, A30i = hr3*hi0 - hi3*hr0;
  float A31r = hr3*hr1 + hi3*hi1, A31i = hr3*hi1 - hi3*hr1;
  float A32r = hr3*hr2 + hi3*hi2, A32i = hr3*hi2 - hi3*hr2;
  float w0r = hr0*yr + hi0*yi, w0i = hr0*yi - hi0*yr;
  float w1r = hr1*yr + hi1*yi, w1i = hr1*yi - hi1*yr;
  float w2r = hr2*yr + hi2*yi, w2i = hr2*yi - hi2*yr;
  float w3r = hr3*yr + hi3*yi, w3i = hr3*yi - hi3*yr;

  // --- butterfly reduce the 24 values across the 8-lane group ---
  BFLY(Ad0) BFLY(Ad1) BFLY(Ad2) BFLY(Ad3)
  BFLY(A10r) BFLY(A10i) BFLY(A20r) BFLY(A20i) BFLY(A21r) BFLY(A21i)
  BFLY(A30r) BFLY(A30i) BFLY(A31r) BFLY(A31i) BFLY(A32r) BFLY(A32i)
  BFLY(w0r) BFLY(w0i) BFLY(w1r) BFLY(w1i)
  BFLY(w2r) BFLY(w2i) BFLY(w3r) BFLY(w3i)

  // --- LDL^H factorization (all lanes duplicate; values bitwise identical) ---
  float Dv0 = Ad0 + no_f;
  float iD0 = 1.0f / Dv0;
  float L10r = A10r*iD0, L10i = A10i*iD0;
  float L20r = A20r*iD0, L20i = A20i*iD0;
  float L30r = A30r*iD0, L30i = A30i*iD0;
  float Dv1 = Ad1 + no_f - (L10r*L10r + L10i*L10i)*Dv0;
  float iD1 = 1.0f / Dv1;
  float t21r = A21r - (L20r*L10r + L20i*L10i)*Dv0;
  float t21i = A21i - (L20i*L10r - L20r*L10i)*Dv0;
  float L21r = t21r*iD1, L21i = t21i*iD1;
  float t31r = A31r - (L30r*L10r + L30i*L10i)*Dv0;
  float t31i = A31i - (L30i*L10r - L30r*L10i)*Dv0;
  float L31r = t31r*iD1, L31i = t31i*iD1;
  float Dv2 = Ad2 + no_f - (L20r*L20r + L20i*L20i)*Dv0 - (L21r*L21r + L21i*L21i)*Dv1;
  float iD2 = 1.0f / Dv2;
  float t32r = A32r - (L30r*L20r + L30i*L20i)*Dv0 - (L31r*L21r + L31i*L21i)*Dv1;
  float t32i = A32i - (L30i*L20r - L30r*L20i)*Dv0 - (L31i*L21r - L31r*L21i)*Dv1;
  float L32r = t32r*iD2, L32i = t32i*iD2;
  float Dv3 = Ad3 + no_f - (L30r*L30r + L30i*L30i)*Dv0 - (L31r*L31r + L31i*L31i)*Dv1
                        - (L32r*L32r + L32i*L32i)*Dv2;
  float iD3 = 1.0f / Dv3;

  // --- solve A z = w ---
  float c0r = w0r, c0i = w0i;
  float c1r = w1r - (L10r*c0r - L10i*c0i);
  float c1i = w1i - (L10r*c0i + L10i*c0r);
  float c2r = w2r - (L20r*c0r - L20i*c0i) - (L21r*c1r - L21i*c1i);
  float c2i = w2i - (L20r*c0i + L20i*c0r) - (L21r*c1i + L21i*c1r);
  float c3r = w3r - (L30r*c0r - L30i*c0i) - (L31r*c1r - L31i*c1i) - (L32r*c2r - L32i*c2i);
  float c3i = w3i - (L30r*c0i + L30i*c0r) - (L31r*c1i + L31i*c1r) - (L32r*c2i + L32i*c2r);
  c0r *= iD0; c0i *= iD0;
  c1r *= iD1; c1i *= iD1;
  c2r *= iD2; c2i *= iD2;
  c3r *= iD3; c3i *= iD3;
  float z3r = c3r, z3i = c3i;
  float z2r = c2r - (L32r*z3r + L32i*z3i);
  float z2i = c2i - (L32r*z3i - L32i*z3r);
  float z1r = c1r - (L21r*z2r + L21i*z2i) - (L31r*z3r + L31i*z3i);
  float z1i = c1i - (L21r*z2i - L21i*z2r) - (L31r*z3i - L31i*z3r);
  float z0r = c0r - (L10r*z1r + L10i*z1i) - (L20r*z2r + L20i*z2i) - (L30r*z3r + L30i*z3i);
  float z0i = c0i - (L10r*z1i - L10i*z1r) - (L20r*z2i - L20i*z2r) - (L30r*z3i - L30i*z3r);

  // --- diag(A^-1) via M = L^-1 ---
  float M10r = -L10r, M10i = -L10i;
  float M21r = -L21r, M21i = -L21i;
  float M32r = -L32r, M32i = -L32i;
  float M20r = -L20r - (L21r*M10r - L21i*M10i);
  float M20i = -L20i - (L21r*M10i + L21i*M10r);
  float M31r = -L31r - (L32r*M21r - L32i*M21i);
  float M31i = -L31i - (L32r*M21i + L32i*M21r);
  float M30r = -L30r - (L31r*M10r - L31i*M10i) - (L32r*M20r - L32i*M20i);
  float M30i = -L30i - (L31r*M10i + L31i*M10r) - (L32r*M20i + L32i*M20r);
  float Ai0 = iD0 + (M10r*M10r + M10i*M10i)*iD1 + (M20r*M20r + M20i*M20i)*iD2
                  + (M30r*M30r + M30i*M30i)*iD3;
  float Ai1 = iD1 + (M21r*M21r + M21i*M21i)*iD2 + (M31r*M31r + M31i*M31i)*iD3;
  float Ai2 = iD2 + (M32r*M32r + M32i*M32i)*iD3;
  float Ai3 = iD3;

  if (r == 0) {
    float zrv[4] = {z0r, z1r, z2r, z3r};
    float ziv[4] = {z0i, z1i, z2i, z3i};
    float Aiv[4] = {Ai0, Ai1, Ai2, Ai3};
#pragma unroll
    for (int s = 0; s < S_; ++s) {
      float dgg = 1.0f - no_f * Aiv[s];
      float dg = fminf(fmaxf(dgg, 1e-6f), (float)(1.0 - 1e-6));
      float xhr = zrv[s] / dg;
      float xhi = ziv[s] / dg;
      float noe = (1.0f - dg) / dg;
      float sc = -2.8284270763397217f / noe;
      float2 o;
      o.x = -(sc * xhr);
      o.y = -(sc * xhi);
      size_t w = (size_t)(b * S_ + s);
      if (k2 < K_) {
        *reinterpret_cast<float2*>(outf + w * K_ + k2) = o;
      } else {
        *reinterpret_cast<float2*>(outf + (size_t)BSK + w * K_ + (k2 - K_)) = o;
      }
    }
  }
}

__global__ __launch_bounds__(256) void bp_kernel(const int* __restrict__ bbits,
                                                 int* __restrict__ out) {
#pragma clang fp contract(off)
  __shared__ float tot[K_];
  __shared__ float E0[K_];  // E0[n] = c2v slot-0 of check n
  __shared__ float E1[K_];  // E1[n] = c2v slot-1 of check (n+7)%K
  __shared__ float E2[K_];  // E2[n] = c2v slot-2 of check (n+150)%K
  int w = blockIdx.x;
  int tid = threadIdx.x;
  const float* outf = (const float*)out;
  bool act = tid < NTH;

  float Lv[4], LP[4];
  float c0v[4] = {0.f,0.f,0.f,0.f};
  float c1v[4] = {0.f,0.f,0.f,0.f};
  float c2v_[4] = {0.f,0.f,0.f,0.f};
  float c3v[4] = {0.f,0.f,0.f,0.f};

  if (act) {
#pragma unroll
    for (int k = 0; k < 4; ++k) {
      int n = tid + NTH * k;
      Lv[k] = outf[(size_t)w * K_ + n];
      LP[k] = outf[(size_t)BSK + (size_t)w * K_ + n];
      E0[n] = 0.f; E1[n] = 0.f; E2[n] = 0.f;
    }
  }
  __syncthreads();

  for (int it = 0; it < BP_ITERS; ++it) {
    // phase A: tot[n] = L[n] + ((E0+E1)+E2)   (matches reference scatter order)
    if (act) {
#pragma unroll
      for (int k = 0; k < 4; ++k) {
        int n = tid + NTH * k;
        tot[n] = Lv[k] + ((E0[n] + E1[n]) + E2[n]);
      }
    }
    __syncthreads();
    // phase B: per-check min-sum, c2v in registers, write shifted E arrays
    if (act) {
#pragma unroll
      for (int k = 0; k < 4; ++k) {
        int c = tid + NTH * k;
        int i1 = c - 7;   if (i1 < 0) i1 += K_;
        int i2 = c - 150; if (i2 < 0) i2 += K_;
        float m0 = tot[c]  - c0v[k];
        float m1 = tot[i1] - c1v[k];
        float m2 = tot[i2] - c2v_[k];
        float totP = LP[k] + c3v[k];      // keep exact reference rounding
        float m3 = totP - c3v[k];
        float a0 = fabsf(m0), a1 = fabsf(m1), a2 = fabsf(m2), a3 = fabsf(m3);
        float t01 = fminf(a0, a1), t23 = fminf(a2, a3);
        float e0 = fminf(a1, t23);
        float e1 = fminf(a0, t23);
        float e2 = fminf(t01, a3);
        float e3 = fminf(t01, a2);
        unsigned s0 = __float_as_uint(m0) & 0x80000000u;
        unsigned s1 = __float_as_uint(m1) & 0x80000000u;
        unsigned s2 = __float_as_uint(m2) & 0x80000000u;
        unsigned s3 = __float_as_uint(m3) & 0x80000000u;
        unsigned sp = (s0 ^ s1) ^ (s2 ^ s3);
        float n0 = __uint_as_float(__float_as_uint(e0) ^ (sp ^ s0));
        float n1 = __uint_as_float(__float_as_uint(e1) ^ (sp ^ s1));
        float n2 = __uint_as_float(__float_as_uint(e2) ^ (sp ^ s2));
        float n3 = __uint_as_float(__float_as_uint(e3) ^ (sp ^ s3));
        c0v[k] = n0; c1v[k] = n1; c2v_[k] = n2; c3v[k] = n3;
        E0[c] = n0; E1[i1] = n1; E2[i2] = n2;
      }
    }
    __syncthreads();
  }

  // final: hard decisions + b_bits copy
  if (act) {
#pragma unroll
    for (int k = 0; k < 4; ++k) {
      int n = tid + NTH * k;
      float ttt = Lv[k] + ((E0[n] + E1[n]) + E2[n]);
      out[(size_t)BSK + (size_t)w * K_ + n] = (ttt < 0.f) ? 1 : 0;
      out[(size_t)w * K_ + n] = bbits[(size_t)w * K_ + n];
    }
  }
}

extern "C" void kernel_launch(void* const* d_in, const int* in_sizes, int n_in,
                              void* d_out, int out_size, void* d_ws, size_t ws_size,
                              hipStream_t stream) {
  const int*   b_bits = (const int*)d_in[0];
  const float* h_real = (const float*)d_in[1];
  const float* h_imag = (const float*)d_in[2];
  const float* n_real = (const float*)d_in[3];
  const float* n_imag = (const float*)d_in[4];
  const int*   ebno   = (const int*)d_in[5];
  int* out = (int*)d_out;
  float* cst = (float*)d_ws;

  setup_kernel<<<1, 1, 0, stream>>>(ebno, cst);
  // 8 lanes per (b,d): B*D*8 threads total
  mmse_llr_kernel<<<(B_ * D_ * 8) / 256, 256, 0, stream>>>(
      b_bits, h_real, h_imag, n_real, n_imag, cst, (float*)d_out);
  bp_kernel<<<B_ * S_, 256, 0, stream>>>(b_bits, out);
}

// Round 5
// 61.061 us; speedup vs baseline: 1.6698x; 1.6698x over previous
//
#include <hip/hip_runtime.h>

#define B_ 512
#define S_ 4
#define K_ 912
#define R_ 8
#define D_ 912
#define NCODE 1824
#define BSK (B_*S_*K_)   /* 1867776 */
#define BP_ITERS 10
#define NTH 228          /* 4*228 = 912 */

// one-thread kernel: compute no / noise-scale once (fp64 pow off the hot path)
__global__ void setup_kernel(const int* __restrict__ ebno, float* __restrict__ cst) {
  int ei = ebno[0];
  float ef = (ei >= -100 && ei <= 100) ? (float)ei : __int_as_float(ei);
  double no_d = pow(10.0, -(double)ef / 10.0);
  cst[0] = (float)no_d;
  cst[1] = (float)sqrt(no_d * 0.5);
}

#define BFLY1(v) { v += __shfl_xor(v, 1); }

// 2 lanes per (b,d): lane half owns antennas half*4..half*4+3.
// Coalesced float4 loads (64B lane stride in a 4KB wave window),
// one-shuffle pairwise reduction, solve duplicated 2x only.
__global__ __launch_bounds__(256) void mmse_llr_kernel(
    const int* __restrict__ bbits, const float* __restrict__ hre,
    const float* __restrict__ him, const float* __restrict__ nre,
    const float* __restrict__ nim, const float* __restrict__ cst,
    float* __restrict__ outf) {
#pragma clang fp contract(off)
  int t = blockIdx.x * 256 + threadIdx.x;
  int g = t >> 1;          // (b,d) group index
  int half = t & 1;        // which 4-antenna half this lane owns
  int b = g / D_;
  int d = g - b * D_;

  const float no_f = cst[0];
  const float nscale = cst[1];
  const float INV2 = 0.70710678118654752440f;

  // --- QPSK symbols for the 4 streams at subcarrier d (dup across 2 lanes) ---
  float xr[S_], xq[S_];
  int k2 = 2 * d;
#pragma unroll
  for (int s = 0; s < S_; ++s) {
    const int* bb = bbits + (b * S_ + s) * K_;
    int c0, c1;
    if (k2 < K_) {
      c0 = bb[k2];
      c1 = bb[k2 + 1];
    } else {
      int j0 = k2 - K_, j1 = k2 + 1 - K_;
      int j0a = j0 - 7;   if (j0a < 0) j0a += K_;
      int j0b = j0 - 150; if (j0b < 0) j0b += K_;
      c0 = (bb[j0] + bb[j0a] + bb[j0b]) & 1;
      int j1a = j1 - 7;   if (j1a < 0) j1a += K_;
      int j1b = j1 - 150; if (j1b < 0) j1b += K_;
      c1 = (bb[j1] + bb[j1a] + bb[j1b]) & 1;
    }
    xr[s] = (1.0f - 2.0f * (float)c0) * INV2;
    xq[s] = (1.0f - 2.0f * (float)c1) * INV2;
  }

  // --- noise for this lane's 4 antennas (float4 at global tid: coalesced) ---
  float4 nr4v = reinterpret_cast<const float4*>(nre)[t];
  float4 ni4v = reinterpret_cast<const float4*>(nim)[t];
  float nrv[4] = {nr4v.x, nr4v.y, nr4v.z, nr4v.w};
  float niv[4] = {ni4v.x, ni4v.y, ni4v.z, ni4v.w};

  const float4* hre4 = reinterpret_cast<const float4*>(hre);
  const float4* him4 = reinterpret_cast<const float4*>(him);

  float Ad0=0.f, Ad1=0.f, Ad2=0.f, Ad3=0.f;
  float A10r=0.f,A10i=0.f,A20r=0.f,A20i=0.f,A21r=0.f,A21i=0.f;
  float A30r=0.f,A30i=0.f,A31r=0.f,A31i=0.f,A32r=0.f,A32i=0.f;
  float w0r=0.f,w0i=0.f,w1r=0.f,w1i=0.f,w2r=0.f,w2i=0.f,w3r=0.f,w3i=0.f;

#pragma unroll
  for (int q = 0; q < 4; ++q) {
    // h row for antenna (half*4+q): float4 index t*4+q (64B lane stride)
    float4 h4r = hre4[(size_t)t * 4 + q];
    float4 h4i = him4[(size_t)t * 4 + q];
    float hr0=h4r.x*INV2, hr1=h4r.y*INV2, hr2=h4r.z*INV2, hr3=h4r.w*INV2;
    float hi0=h4i.x*INV2, hi1=h4i.y*INV2, hi2=h4i.z*INV2, hi3=h4i.w*INV2;
    float yr = 0.f, yi = 0.f;
    yr += hr0*xr[0] - hi0*xq[0]; yi += hr0*xq[0] + hi0*xr[0];
    yr += hr1*xr[1] - hi1*xq[1]; yi += hr1*xq[1] + hi1*xr[1];
    yr += hr2*xr[2] - hi2*xq[2]; yi += hr2*xq[2] + hi2*xr[2];
    yr += hr3*xr[3] - hi3*xq[3]; yi += hr3*xq[3] + hi3*xr[3];
    yr += nrv[q]*nscale; yi += niv[q]*nscale;
    Ad0 += hr0*hr0 + hi0*hi0;
    Ad1 += hr1*hr1 + hi1*hi1;
    Ad2 += hr2*hr2 + hi2*hi2;
    Ad3 += hr3*hr3 + hi3*hi3;
    A10r += hr1*hr0 + hi1*hi0;  A10i += hr1*hi0 - hi1*hr0;
    A20r += hr2*hr0 + hi2*hi0;  A20i += hr2*hi0 - hi2*hr0;
    A21r += hr2*hr1 + hi2*hi1;  A21i += hr2*hi1 - hi2*hr1;
    A30r += hr3*hr0 + hi3*hi0;  A30i += hr3*hi0 - hi3*hr0;
    A31r += hr3*hr1 + hi3*hi1;  A31i += hr3*hi1 - hi3*hr1;
    A32r += hr3*hr2 + hi3*hi2;  A32i += hr3*hi2 - hi3*hr2;
    w0r += hr0*yr + hi0*yi;  w0i += hr0*yi - hi0*yr;
    w1r += hr1*yr + hi1*yi;  w1i += hr1*yi - hi1*yr;
    w2r += hr2*yr + hi2*yi;  w2i += hr2*yi - hi2*yr;
    w3r += hr3*yr + hi3*yi;  w3i += hr3*yi - hi3*yr;
  }

  // --- pairwise reduce across the 2-lane group (both lanes get identical sums) ---
  BFLY1(Ad0) BFLY1(Ad1) BFLY1(Ad2) BFLY1(Ad3)
  BFLY1(A10r) BFLY1(A10i) BFLY1(A20r) BFLY1(A20i) BFLY1(A21r) BFLY1(A21i)
  BFLY1(A30r) BFLY1(A30i) BFLY1(A31r) BFLY1(A31i) BFLY1(A32r) BFLY1(A32i)
  BFLY1(w0r) BFLY1(w0i) BFLY1(w1r) BFLY1(w1i)
  BFLY1(w2r) BFLY1(w2i) BFLY1(w3r) BFLY1(w3i)

  // --- LDL^H factorization (dup 2x; values bitwise identical across the pair) ---
  float Dv0 = Ad0 + no_f;
  float iD0 = 1.0f / Dv0;
  float L10r = A10r*iD0, L10i = A10i*iD0;
  float L20r = A20r*iD0, L20i = A20i*iD0;
  float L30r = A30r*iD0, L30i = A30i*iD0;
  float Dv1 = Ad1 + no_f - (L10r*L10r + L10i*L10i)*Dv0;
  float iD1 = 1.0f / Dv1;
  float t21r = A21r - (L20r*L10r + L20i*L10i)*Dv0;
  float t21i = A21i - (L20i*L10r - L20r*L10i)*Dv0;
  float L21r = t21r*iD1, L21i = t21i*iD1;
  float t31r = A31r - (L30r*L10r + L30i*L10i)*Dv0;
  float t31i = A31i - (L30i*L10r - L30r*L10i)*Dv0;
  float L31r = t31r*iD1, L31i = t31i*iD1;
  float Dv2 = Ad2 + no_f - (L20r*L20r + L20i*L20i)*Dv0 - (L21r*L21r + L21i*L21i)*Dv1;
  float iD2 = 1.0f / Dv2;
  float t32r = A32r - (L30r*L20r + L30i*L20i)*Dv0 - (L31r*L21r + L31i*L21i)*Dv1;
  float t32i = A32i - (L30i*L20r - L30r*L20i)*Dv0 - (L31i*L21r - L31r*L21i)*Dv1;
  float L32r = t32r*iD2, L32i = t32i*iD2;
  float Dv3 = Ad3 + no_f - (L30r*L30r + L30i*L30i)*Dv0 - (L31r*L31r + L31i*L31i)*Dv1
                        - (L32r*L32r + L32i*L32i)*Dv2;
  float iD3 = 1.0f / Dv3;

  // --- solve A z = w ---
  float c0r = w0r, c0i = w0i;
  float c1r = w1r - (L10r*c0r - L10i*c0i);
  float c1i = w1i - (L10r*c0i + L10i*c0r);
  float c2r = w2r - (L20r*c0r - L20i*c0i) - (L21r*c1r - L21i*c1i);
  float c2i = w2i - (L20r*c0i + L20i*c0r) - (L21r*c1i + L21i*c1r);
  float c3r = w3r - (L30r*c0r - L30i*c0i) - (L31r*c1r - L31i*c1i) - (L32r*c2r - L32i*c2i);
  float c3i = w3i - (L30r*c0i + L30i*c0r) - (L31r*c1i + L31i*c1r) - (L32r*c2i + L32i*c2r);
  c0r *= iD0; c0i *= iD0;
  c1r *= iD1; c1i *= iD1;
  c2r *= iD2; c2i *= iD2;
  c3r *= iD3; c3i *= iD3;
  float z3r = c3r, z3i = c3i;
  float z2r = c2r - (L32r*z3r + L32i*z3i);
  float z2i = c2i - (L32r*z3i - L32i*z3r);
  float z1r = c1r - (L21r*z2r + L21i*z2i) - (L31r*z3r + L31i*z3i);
  float z1i = c1i - (L21r*z2i - L21i*z2r) - (L31r*z3i - L31i*z3r);
  float z0r = c0r - (L10r*z1r + L10i*z1i) - (L20r*z2r + L20i*z2i) - (L30r*z3r + L30i*z3i);
  float z0i = c0i - (L10r*z1i - L10i*z1r) - (L20r*z2i - L20i*z2r) - (L30r*z3i - L30i*z3r);

  // --- diag(A^-1) via M = L^-1 ---
  float M10r = -L10r, M10i = -L10i;
  float M21r = -L21r, M21i = -L21i;
  float M32r = -L32r, M32i = -L32i;
  float M20r = -L20r - (L21r*M10r - L21i*M10i);
  float M20i = -L20i - (L21r*M10i + L21i*M10r);
  float M31r = -L31r - (L32r*M21r - L32i*M21i);
  float M31i = -L31i - (L32r*M21i + L32i*M21r);
  float M30r = -L30r - (L31r*M10r - L31i*M10i) - (L32r*M20r - L32i*M20i);
  float M30i = -L30i - (L31r*M10i + L31i*M10r) - (L32r*M20i + L32i*M20r);
  float Ai0 = iD0 + (M10r*M10r + M10i*M10i)*iD1 + (M20r*M20r + M20i*M20i)*iD2
                  + (M30r*M30r + M30i*M30i)*iD3;
  float Ai1 = iD1 + (M21r*M21r + M21i*M21i)*iD2 + (M31r*M31r + M31i*M31i)*iD3;
  float Ai2 = iD2 + (M32r*M32r + M32i*M32i)*iD3;
  float Ai3 = iD3;

  float zrv[4] = {z0r, z1r, z2r, z3r};
  float ziv[4] = {z0i, z1i, z2i, z3i};
  float Aiv[4] = {Ai0, Ai1, Ai2, Ai3};

  // --- each lane writes 2 of the 4 streams' LLR pairs ---
#pragma unroll
  for (int j = 0; j < 2; ++j) {
    int s = half * 2 + j;
    float dgg = 1.0f - no_f * Aiv[s];
    float dg = fminf(fmaxf(dgg, 1e-6f), (float)(1.0 - 1e-6));
    float xhr = zrv[s] / dg;
    float xhi = ziv[s] / dg;
    float noe = (1.0f - dg) / dg;
    float sc = -2.8284270763397217f / noe;
    float2 o;
    o.x = -(sc * xhr);
    o.y = -(sc * xhi);
    size_t w = (size_t)(b * S_ + s);
    if (k2 < K_) {
      *reinterpret_cast<float2*>(outf + w * K_ + k2) = o;
    } else {
      *reinterpret_cast<float2*>(outf + (size_t)BSK + w * K_ + (k2 - K_)) = o;
    }
  }
}

__global__ __launch_bounds__(256) void bp_kernel(const int* __restrict__ bbits,
                                                 int* __restrict__ out) {
#pragma clang fp contract(off)
  __shared__ float tot[K_];
  __shared__ float E0[K_];  // E0[n] = c2v slot-0 of check n
  __shared__ float E1[K_];  // E1[n] = c2v slot-1 of check (n+7)%K
  __shared__ float E2[K_];  // E2[n] = c2v slot-2 of check (n+150)%K
  int w = blockIdx.x;
  int tid = threadIdx.x;
  const float* outf = (const float*)out;
  bool act = tid < NTH;

  float Lv[4], LP[4];
  float c0v[4] = {0.f,0.f,0.f,0.f};
  float c1v[4] = {0.f,0.f,0.f,0.f};
  float c2v_[4] = {0.f,0.f,0.f,0.f};
  float c3v[4] = {0.f,0.f,0.f,0.f};

  if (act) {
#pragma unroll
    for (int k = 0; k < 4; ++k) {
      int n = tid + NTH * k;
      Lv[k] = outf[(size_t)w * K_ + n];
      LP[k] = outf[(size_t)BSK + (size_t)w * K_ + n];
      E0[n] = 0.f; E1[n] = 0.f; E2[n] = 0.f;
    }
  }
  __syncthreads();

  for (int it = 0; it < BP_ITERS; ++it) {
    // phase A: tot[n] = L[n] + ((E0+E1)+E2)   (matches reference scatter order)
    if (act) {
#pragma unroll
      for (int k = 0; k < 4; ++k) {
        int n = tid + NTH * k;
        tot[n] = Lv[k] + ((E0[n] + E1[n]) + E2[n]);
      }
    }
    __syncthreads();
    // phase B: per-check min-sum, c2v in registers, write shifted E arrays
    if (act) {
#pragma unroll
      for (int k = 0; k < 4; ++k) {
        int c = tid + NTH * k;
        int i1 = c - 7;   if (i1 < 0) i1 += K_;
        int i2 = c - 150; if (i2 < 0) i2 += K_;
        float m0 = tot[c]  - c0v[k];
        float m1 = tot[i1] - c1v[k];
        float m2 = tot[i2] - c2v_[k];
        float totP = LP[k] + c3v[k];      // keep exact reference rounding
        float m3 = totP - c3v[k];
        float a0 = fabsf(m0), a1 = fabsf(m1), a2 = fabsf(m2), a3 = fabsf(m3);
        float t01 = fminf(a0, a1), t23 = fminf(a2, a3);
        float e0 = fminf(a1, t23);
        float e1 = fminf(a0, t23);
        float e2 = fminf(t01, a3);
        float e3 = fminf(t01, a2);
        unsigned s0 = __float_as_uint(m0) & 0x80000000u;
        unsigned s1 = __float_as_uint(m1) & 0x80000000u;
        unsigned s2 = __float_as_uint(m2) & 0x80000000u;
        unsigned s3 = __float_as_uint(m3) & 0x80000000u;
        unsigned sp = (s0 ^ s1) ^ (s2 ^ s3);
        float n0 = __uint_as_float(__float_as_uint(e0) ^ (sp ^ s0));
        float n1 = __uint_as_float(__float_as_uint(e1) ^ (sp ^ s1));
        float n2 = __uint_as_float(__float_as_uint(e2) ^ (sp ^ s2));
        float n3 = __uint_as_float(__float_as_uint(e3) ^ (sp ^ s3));
        c0v[k] = n0; c1v[k] = n1; c2v_[k] = n2; c3v[k] = n3;
        E0[c] = n0; E1[i1] = n1; E2[i2] = n2;
      }
    }
    __syncthreads();
  }

  // final: hard decisions + b_bits copy
  if (act) {
#pragma unroll
    for (int k = 0; k < 4; ++k) {
      int n = tid + NTH * k;
      float ttt = Lv[k] + ((E0[n] + E1[n]) + E2[n]);
      out[(size_t)BSK + (size_t)w * K_ + n] = (ttt < 0.f) ? 1 : 0;
      out[(size_t)w * K_ + n] = bbits[(size_t)w * K_ + n];
    }
  }
}

extern "C" void kernel_launch(void* const* d_in, const int* in_sizes, int n_in,
                              void* d_out, int out_size, void* d_ws, size_t ws_size,
                              hipStream_t stream) {
  const int*   b_bits = (const int*)d_in[0];
  const float* h_real = (const float*)d_in[1];
  const float* h_imag = (const float*)d_in[2];
  const float* n_real = (const float*)d_in[3];
  const float* n_imag = (const float*)d_in[4];
  const int*   ebno   = (const int*)d_in[5];
  int* out = (int*)d_out;
  float* cst = (float*)d_ws;

  setup_kernel<<<1, 1, 0, stream>>>(ebno, cst);
  // 2 lanes per (b,d): B*D*2 threads total
  mmse_llr_kernel<<<(B_ * D_ * 2) / 256, 256, 0, stream>>>(
      b_bits, h_real, h_imag, n_real, n_imag, cst, (float*)d_out);
  bp_kernel<<<B_ * S_, 256, 0, stream>>>(b_bits, out);
}